// Round 3
// baseline (322.330 us; speedup 1.0000x reference)
//
#include <hip/hip_runtime.h>
#include <math.h>

// Problem constants
#define LAM_INIT 0.2f
#define ONE_MINUS_LAM 0.8f
#define SCALING_F 0.05103103630798288f  // 384^-0.5

__device__ inline float waveMax(float v) {
#pragma unroll
    for (int o = 32; o > 0; o >>= 1) v = fmaxf(v, __shfl_xor(v, o));
    return v;
}
__device__ inline float waveMin(float v) {
#pragma unroll
    for (int o = 32; o > 0; o >>= 1) v = fminf(v, __shfl_xor(v, o));
    return v;
}
__device__ inline float waveSum(float v) {
#pragma unroll
    for (int o = 32; o > 0; o >>= 1) v += __shfl_xor(v, o);
    return v;
}

// ---------------------------------------------------------------------------
// K01: fused prep. 1281 blocks:
//  [0,128):   transpose key (B,L,32) -> keyT (B,32,L)
//  [128,512): Wcomb split-K x2: Wcomb[e*64+h*32+g] += SCALING * sum_{d half} ...
//  [512,1280): Wvo split-K x8: Wvo[g*768+e] += sum_{c chunk} Wv[g,c]*ln[c]*Wout[c,e]
//  [1280]:    lam scalar
// Wcomb/Wvo accumulated with atomicAdd into pre-zeroed ws.
// ---------------------------------------------------------------------------
__global__ __launch_bounds__(256) void k01_prep(
    const float* __restrict__ key, const float* __restrict__ Wq,
    const float* __restrict__ Wkv, const float* __restrict__ Wout,
    const float* __restrict__ lq1, const float* __restrict__ lk1,
    const float* __restrict__ lq2, const float* __restrict__ lk2,
    const float* __restrict__ ln,
    float* __restrict__ keyT, float* __restrict__ Wcomb,
    float* __restrict__ Wvo, float* __restrict__ lam)
{
    int blk = blockIdx.x;
    int tid = threadIdx.x;
    if (blk < 128) {
        // --- transpose ---
        int b  = blk >> 4;
        int l0 = (blk & 15) << 8;
        __shared__ float tile[256 * 33];
        const float* kp = key + ((size_t)b * 4096 + l0) * 32;
#pragma unroll
        for (int q = 0; q < 32; ++q) {
            int idx = tid + (q << 8);
            int r = idx >> 5, g = idx & 31;
            tile[r * 33 + g] = kp[idx];
        }
        __syncthreads();
        float* op = keyT + (size_t)b * 32 * 4096 + l0;
#pragma unroll
        for (int q = 0; q < 32; ++q) {
            int idx = tid + (q << 8);
            int g = idx >> 8, ll = idx & 255;
            op[(size_t)g * 4096 + ll] = tile[ll * 33 + g];
        }
    } else if (blk < 512) {
        // --- Wcomb, split-K x2 ---
        int bb = blk - 128;          // 0..383
        int kc = bb & 1;
        int ob = bb >> 1;            // 0..191
        int idx = ob * 256 + tid;    // 0..49151
        int e  = idx >> 6;
        int hg = idx & 63;
        int h = hg >> 5, g = hg & 31;
        const float4* wqr = (const float4*)(Wq  + (size_t)e * 768 + h * 384 + kc * 192);
        const float4* wkr = (const float4*)(Wkv + (size_t)g * 1536 + h * 384 + kc * 192);
        float s0 = 0.f, s1 = 0.f;
#pragma unroll 4
        for (int d = 0; d < 48; d += 2) {
            float4 a0 = wqr[d],   b0 = wkr[d];
            float4 a1 = wqr[d+1], b1 = wkr[d+1];
            s0 += a0.x*b0.x + a0.y*b0.y + a0.z*b0.z + a0.w*b0.w;
            s1 += a1.x*b1.x + a1.y*b1.y + a1.z*b1.z + a1.w*b1.w;
        }
        atomicAdd(&Wcomb[idx], (s0 + s1) * SCALING_F);
    } else if (blk < 1280) {
        // --- Wvo, split-K x8 ---
        int bb = blk - 512;          // 0..767
        int kc = bb / 96;            // 0..7
        int ob = bb - kc * 96;       // 0..95
        int idx = ob * 256 + tid;    // 0..24575
        int g = idx / 768;
        int e = idx - g * 768;
        const float* wvr = Wkv + (size_t)g * 1536 + 768;
        int c0 = kc * 96;
        float s0 = 0.f, s1 = 0.f;
#pragma unroll 4
        for (int c = c0; c < c0 + 96; c += 2) {
            s0 += wvr[c]   * ln[c]   * Wout[(size_t)c * 768 + e];
            s1 += wvr[c+1] * ln[c+1] * Wout[(size_t)(c+1) * 768 + e];
        }
        atomicAdd(&Wvo[idx], s0 + s1);
    } else {
        // --- lambda ---
        float s1 = 0.f, s2 = 0.f;
        for (int d = tid; d < 384; d += 256) {
            s1 += lq1[d] * lk1[d];
            s2 += lq2[d] * lk2[d];
        }
        s1 = waveSum(s1);
        s2 = waveSum(s2);
        __shared__ float r1[4], r2[4];
        int wid = tid >> 6, lane = tid & 63;
        if (lane == 0) { r1[wid] = s1; r2[wid] = s2; }
        __syncthreads();
        if (tid == 0) {
            float a  = r1[0] + r1[1] + r1[2] + r1[3];
            float b2 = r2[0] + r2[1] + r2[2] + r2[3];
            lam[0] = expf(a) - expf(b2) + LAM_INIT;
        }
    }
}

// ---------------------------------------------------------------------------
// K2: Qt[m, n] = query[m, :768] @ Wcomb[:768, n]   (M=4096, N=64, K=768)
// 128 blocks, tile 32m x 64n, BK=32, thread = 2m x 4n.
// ---------------------------------------------------------------------------
__global__ __launch_bounds__(256) void k2_qt(
    const float* __restrict__ query, const float* __restrict__ Wcomb,
    float* __restrict__ Qt)
{
    int m0 = blockIdx.x * 32;
    int tid = threadIdx.x;
    int tx = tid & 15;       // col group: cols tx*4 .. +3
    int ty = tid >> 4;       // row group: rows ty*2 .. +1
    __shared__ __align__(16) float As[32 * 36];  // 32 rows x 32 k, pad 36
    __shared__ __align__(16) float Bs[32 * 64];  // 32 k x 64 n
    float acc[2][4] = {{0.f,0.f,0.f,0.f},{0.f,0.f,0.f,0.f}};

    for (int k0 = 0; k0 < 768; k0 += 32) {
        __syncthreads();
#pragma unroll
        for (int q = 0; q < 4; ++q) {
            int idx = tid + q * 256;       // 1024 elems
            int r = idx >> 5, c = idx & 31;
            As[r * 36 + c] = query[(size_t)(m0 + r) * 768 + k0 + c];
        }
#pragma unroll
        for (int q = 0; q < 8; ++q) {
            int idx = tid + q * 256;       // 2048 elems
            int r = idx >> 6, c = idx & 63;
            Bs[r * 64 + c] = Wcomb[(size_t)(k0 + r) * 64 + c];
        }
        __syncthreads();
#pragma unroll
        for (int kk = 0; kk < 32; kk += 4) {
            float4 a0 = *(const float4*)&As[(ty * 2 + 0) * 36 + kk];
            float4 a1 = *(const float4*)&As[(ty * 2 + 1) * 36 + kk];
            float4 b0 = *(const float4*)&Bs[(kk + 0) * 64 + tx * 4];
            float4 b1 = *(const float4*)&Bs[(kk + 1) * 64 + tx * 4];
            float4 b2 = *(const float4*)&Bs[(kk + 2) * 64 + tx * 4];
            float4 b3 = *(const float4*)&Bs[(kk + 3) * 64 + tx * 4];
            acc[0][0] += a0.x*b0.x + a0.y*b1.x + a0.z*b2.x + a0.w*b3.x;
            acc[0][1] += a0.x*b0.y + a0.y*b1.y + a0.z*b2.y + a0.w*b3.y;
            acc[0][2] += a0.x*b0.z + a0.y*b1.z + a0.z*b2.z + a0.w*b3.z;
            acc[0][3] += a0.x*b0.w + a0.y*b1.w + a0.z*b2.w + a0.w*b3.w;
            acc[1][0] += a1.x*b0.x + a1.y*b1.x + a1.z*b2.x + a1.w*b3.x;
            acc[1][1] += a1.x*b0.y + a1.y*b1.y + a1.z*b2.y + a1.w*b3.y;
            acc[1][2] += a1.x*b0.z + a1.y*b1.z + a1.z*b2.z + a1.w*b3.z;
            acc[1][3] += a1.x*b0.w + a1.y*b1.w + a1.z*b2.w + a1.w*b3.w;
        }
    }
#pragma unroll
    for (int rr = 0; rr < 2; ++rr) {
        float4 o; o.x = acc[rr][0]; o.y = acc[rr][1]; o.z = acc[rr][2]; o.w = acc[rr][3];
        *(float4*)&Qt[(size_t)(m0 + ty * 2 + rr) * 64 + tx * 4] = o;
    }
}

// ---------------------------------------------------------------------------
// K3 v3: fused scores -> masked softmax -> diff -> min-sub -> write.
// One block per (b, 4 s-rows). 1024 blocks x 256 threads.
// p[2][4][16] = 128 VGPR; thread owns l = c*1024 + tid*4 + j.
// Key L2 traffic: 1024 blocks * 512KB = 512 MB (~15 us); VALU ~28 us floor.
// ---------------------------------------------------------------------------
__global__ __launch_bounds__(256, 2) void k3_attn(
    const float* __restrict__ Qt, const float* __restrict__ keyT,
    const int* __restrict__ qmask, const int* __restrict__ kmask,
    const float* __restrict__ lamp, float* __restrict__ diffO)
{
    int blk = blockIdx.x;
    int b  = blk >> 7;
    int s0 = (blk & 127) * 4;
    int tid = threadIdx.x;
    int lane = tid & 63, wid = tid >> 6;

    __shared__ float qt_s[256];   // [ts*64 + h*32 + g]
    __shared__ float red[32];

    {
        int ts = tid >> 6, c2 = tid & 63;
        qt_s[tid] = Qt[(size_t)(b * 512 + s0 + ts) * 64 + c2];
    }
    int qm[4];
#pragma unroll
    for (int ts = 0; ts < 4; ++ts) qm[ts] = qmask[b * 512 + s0 + ts];
    float lam = lamp[0];

    // kmask bits for the 16 owned l's
    unsigned kmb = 0;
#pragma unroll
    for (int c = 0; c < 4; ++c) {
        int4 km = *(const int4*)(kmask + b * 4096 + c * 1024 + tid * 4);
        if (km.x) kmb |= 1u << (c * 4 + 0);
        if (km.y) kmb |= 1u << (c * 4 + 1);
        if (km.z) kmb |= 1u << (c * 4 + 2);
        if (km.w) kmb |= 1u << (c * 4 + 3);
    }
    __syncthreads();

    float p[2][4][16];   // [h][ts][c*4+j]
#pragma unroll
    for (int h = 0; h < 2; ++h)
#pragma unroll
        for (int ts = 0; ts < 4; ++ts)
#pragma unroll
            for (int i = 0; i < 16; ++i) p[h][ts][i] = 0.f;

    const float* kt = keyT + (size_t)b * 131072 + tid * 4;
    for (int g = 0; g < 32; ++g) {
        float qh[2][4];
#pragma unroll
        for (int ts = 0; ts < 4; ++ts) {
            qh[0][ts] = qt_s[ts * 64 + g];
            qh[1][ts] = qt_s[ts * 64 + 32 + g];
        }
        const float* kg = kt + (size_t)g * 4096;
#pragma unroll
        for (int c = 0; c < 4; ++c) {
            float4 kv = *(const float4*)(kg + c * 1024);
#pragma unroll
            for (int h = 0; h < 2; ++h)
#pragma unroll
                for (int ts = 0; ts < 4; ++ts) {
                    p[h][ts][c*4+0] += qh[h][ts] * kv.x;
                    p[h][ts][c*4+1] += qh[h][ts] * kv.y;
                    p[h][ts][c*4+2] += qh[h][ts] * kv.z;
                    p[h][ts][c*4+3] += qh[h][ts] * kv.w;
                }
        }
    }

    // apply masks
#pragma unroll
    for (int h = 0; h < 2; ++h)
#pragma unroll
        for (int ts = 0; ts < 4; ++ts) {
#pragma unroll
            for (int i = 0; i < 16; ++i) {
                bool ok = qm[ts] && ((kmb >> i) & 1u);
                p[h][ts][i] = ok ? p[h][ts][i] : -1e20f;
            }
        }

    // Phase B1: row max
    float mrow[2][4];
#pragma unroll
    for (int h = 0; h < 2; ++h)
#pragma unroll
        for (int ts = 0; ts < 4; ++ts) {
            float v = -3.4e38f;
#pragma unroll
            for (int i = 0; i < 16; ++i) v = fmaxf(v, p[h][ts][i]);
            v = waveMax(v);
            if (lane == 0) red[(h * 4 + ts) * 4 + wid] = v;
        }
    __syncthreads();
#pragma unroll
    for (int h = 0; h < 2; ++h)
#pragma unroll
        for (int ts = 0; ts < 4; ++ts) {
            int r = (h * 4 + ts) * 4;
            mrow[h][ts] = fmaxf(fmaxf(red[r], red[r + 1]), fmaxf(red[r + 2], red[r + 3]));
        }
    __syncthreads();

    // Phase B2: exp + sum
    float inv[2][4];
#pragma unroll
    for (int h = 0; h < 2; ++h)
#pragma unroll
        for (int ts = 0; ts < 4; ++ts) {
            float s = 0.f;
#pragma unroll
            for (int i = 0; i < 16; ++i) {
                float e2 = __expf(p[h][ts][i] - mrow[h][ts]);
                p[h][ts][i] = e2;
                s += e2;
            }
            s = waveSum(s);
            if (lane == 0) red[(h * 4 + ts) * 4 + wid] = s;
        }
    __syncthreads();
#pragma unroll
    for (int h = 0; h < 2; ++h)
#pragma unroll
        for (int ts = 0; ts < 4; ++ts) {
            int r = (h * 4 + ts) * 4;
            inv[h][ts] = 1.0f / (red[r] + red[r + 1] + red[r + 2] + red[r + 3] + 1e-8f);
        }
    __syncthreads();

    // Phase C: diff + min (d stored over p[0][ts][i])
    float mn[4];
#pragma unroll
    for (int ts = 0; ts < 4; ++ts) {
        float v = 3.4e38f;
#pragma unroll
        for (int i = 0; i < 16; ++i) {
            float d = p[0][ts][i] * inv[0][ts] - lam * (p[1][ts][i] * inv[1][ts]);
            p[0][ts][i] = d;
            v = fminf(v, d);
        }
        v = waveMin(v);
        if (lane == 0) red[ts * 4 + wid] = v;
    }
    __syncthreads();
#pragma unroll
    for (int ts = 0; ts < 4; ++ts) {
        int r = ts * 4;
        mn[ts] = fminf(fminf(red[r], red[r + 1]), fminf(red[r + 2], red[r + 3]));
    }

    // Phase D: write diff output (float4, coalesced)
#pragma unroll
    for (int ts = 0; ts < 4; ++ts) {
        size_t base = (size_t)(b * 512 + s0 + ts) * 4096 + tid * 4;
#pragma unroll
        for (int c = 0; c < 4; ++c) {
            float4 o;
            float v0 = p[0][ts][c*4+0] - mn[ts] + 1e-20f;
            float v1 = p[0][ts][c*4+1] - mn[ts] + 1e-20f;
            float v2 = p[0][ts][c*4+2] - mn[ts] + 1e-20f;
            float v3 = p[0][ts][c*4+3] - mn[ts] + 1e-20f;
            o.x = (qm[ts] && ((kmb >> (c*4+0)) & 1u)) ? v0 : 0.f;
            o.y = (qm[ts] && ((kmb >> (c*4+1)) & 1u)) ? v1 : 0.f;
            o.z = (qm[ts] && ((kmb >> (c*4+2)) & 1u)) ? v2 : 0.f;
            o.w = (qm[ts] && ((kmb >> (c*4+3)) & 1u)) ? v3 : 0.f;
            *(float4*)(diffO + base + c * 1024) = o;
        }
    }
}

// ---------------------------------------------------------------------------
// K4: T[row, g] = sum_l diff[row, l] * key[b, l, g]   (rows=4096, g=32, K=4096)
// 512 blocks = 32 row-tiles(128) x 16 k-chunks(256). key tile in LDS,
// diff via vectorized global (L2/L3-resident). atomicAdd epilogue (T pre-zeroed).
// ---------------------------------------------------------------------------
__global__ __launch_bounds__(256) void k4_T(
    const float* __restrict__ diff, const float* __restrict__ key,
    float* __restrict__ T)
{
    int blk = blockIdx.x;
    int rt = blk & 31, kc = blk >> 5;
    int row0 = rt << 7;     // *128
    int b = row0 >> 9;
    int l0 = kc << 8;       // *256
    int tid = threadIdx.x;
    int tx = tid & 7;       // g0 = tx*4
    int ty = tid >> 3;      // rows row0 + ty*4 + r
    int g0 = tx * 4;

    __shared__ __align__(16) float Ks[256][32];
#pragma unroll
    for (int q = 0; q < 32; ++q) {
        int idx = tid + (q << 8);
        int r = idx >> 5, g = idx & 31;
        Ks[r][g] = key[((size_t)(b * 4096 + l0 + r)) * 32 + g];
    }
    __syncthreads();

    float acc[4][4];
#pragma unroll
    for (int r = 0; r < 4; ++r)
#pragma unroll
        for (int c2 = 0; c2 < 4; ++c2) acc[r][c2] = 0.f;

    for (int j4 = 0; j4 < 64; ++j4) {
        int l = l0 + j4 * 4;
        float4 dv[4];
#pragma unroll
        for (int r = 0; r < 4; ++r)
            dv[r] = *(const float4*)(diff + (size_t)(row0 + ty * 4 + r) * 4096 + l);
#pragma unroll
        for (int jj = 0; jj < 4; ++jj) {
            float4 kq = *(const float4*)&Ks[j4 * 4 + jj][g0];
#pragma unroll
            for (int r = 0; r < 4; ++r) {
                float d = (jj == 0) ? dv[r].x : (jj == 1) ? dv[r].y : (jj == 2) ? dv[r].z : dv[r].w;
                acc[r][0] += d * kq.x;
                acc[r][1] += d * kq.y;
                acc[r][2] += d * kq.z;
                acc[r][3] += d * kq.w;
            }
        }
    }
#pragma unroll
    for (int r = 0; r < 4; ++r)
#pragma unroll
        for (int c2 = 0; c2 < 4; ++c2)
            atomicAdd(&T[(size_t)(row0 + ty * 4 + r) * 32 + g0 + c2], acc[r][c2]);
}

// ---------------------------------------------------------------------------
// K5: per-row RMS statistic from a = T@Wv, then out = 0.8*rs * (T @ Wvo)
// 512 blocks x 8 rows. Thread owns 3 e-columns.
// ---------------------------------------------------------------------------
__global__ __launch_bounds__(256) void k5_out(
    const float* __restrict__ T, const float* __restrict__ Wkv,
    const float* __restrict__ Wvo, float* __restrict__ out)
{
    int row0 = blockIdx.x * 8;
    int tid = threadIdx.x;
    int wid = tid >> 6, lane = tid & 63;
    __shared__ __align__(16) float Ts[8][32];
    __shared__ float red[8][4];
    __shared__ float rs_s[8];

    {
        int r = tid >> 5, g = tid & 31;
        Ts[r][g] = T[(size_t)(row0 + r) * 32 + g];
    }
    __syncthreads();

    float ssq[8];
#pragma unroll
    for (int r = 0; r < 8; ++r) ssq[r] = 0.f;

#pragma unroll
    for (int ec = 0; ec < 3; ++ec) {
        int e = tid + ec * 256;
        float wv[32];
#pragma unroll
        for (int g = 0; g < 32; ++g) wv[g] = Wkv[(size_t)g * 1536 + 768 + e];
#pragma unroll
        for (int r = 0; r < 8; ++r) {
            float a = 0.f;
#pragma unroll
            for (int g = 0; g < 32; ++g) a += Ts[r][g] * wv[g];
            ssq[r] += a * a;
        }
    }
#pragma unroll
    for (int r = 0; r < 8; ++r) {
        float v = waveSum(ssq[r]);
        if (lane == 0) red[r][wid] = v;
    }
    __syncthreads();
    if (tid < 8) {
        float s = red[tid][0] + red[tid][1] + red[tid][2] + red[tid][3];
        float ms = s * (1.0f / 768.0f);
        rs_s[tid] = rsqrtf(ms + 1e-5f) * ONE_MINUS_LAM;
    }
    __syncthreads();

#pragma unroll
    for (int ec = 0; ec < 3; ++ec) {
        int e = tid + ec * 256;
        float wo[32];
#pragma unroll
        for (int g = 0; g < 32; ++g) wo[g] = Wvo[(size_t)g * 768 + e];
#pragma unroll
        for (int r = 0; r < 8; ++r) {
            float o = 0.f;
#pragma unroll
            for (int g = 0; g < 32; ++g) o += Ts[r][g] * wo[g];
            out[(size_t)(row0 + r) * 768 + e] = o * rs_s[r];
        }
    }
}

// ---------------------------------------------------------------------------
extern "C" void kernel_launch(void* const* d_in, const int* in_sizes, int n_in,
                              void* d_out, int out_size, void* d_ws, size_t ws_size,
                              hipStream_t stream) {
    (void)in_sizes; (void)n_in; (void)out_size; (void)ws_size;
    const float* query = (const float*)d_in[0];
    const float* key   = (const float*)d_in[1];
    const int*   qmask = (const int*)d_in[2];
    const int*   kmask = (const int*)d_in[3];
    const float* Wq    = (const float*)d_in[4];
    const float* Wkv   = (const float*)d_in[5];
    const float* Wout  = (const float*)d_in[6];
    const float* lq1   = (const float*)d_in[7];
    const float* lk1   = (const float*)d_in[8];
    const float* lq2   = (const float*)d_in[9];
    const float* lk2   = (const float*)d_in[10];
    const float* ln    = (const float*)d_in[11];

    float* out  = (float*)d_out;          // (B,S,E) = 3,145,728 floats
    float* diff = out + 3145728;          // (B,S,L) = 16,777,216 floats

    float* ws    = (float*)d_ws;
    float* Wcomb = ws;                    // 49152   (zeroed)
    float* Wvo   = ws + 49152;            // 24576   (zeroed)
    float* T     = ws + 73728;            // 131072  (zeroed)
    float* lam   = ws + 204800;           // 64
    float* Qt    = ws + 204864;           // 262144
    float* keyT  = ws + 467008;           // 1048576  -> total ~6.1 MB

    hipMemsetAsync(ws, 0, 204800 * sizeof(float), stream);
    k01_prep<<<1281, 256, 0, stream>>>(key, Wq, Wkv, Wout, lq1, lk1, lq2, lk2, ln,
                                       keyT, Wcomb, Wvo, lam);
    k2_qt<<<128, 256, 0, stream>>>(query, Wcomb, Qt);
    k3_attn<<<1024, 256, 0, stream>>>(Qt, keyT, qmask, kmask, lam, diff);
    k4_T<<<512, 256, 0, stream>>>(diff, key, T);
    k5_out<<<512, 256, 0, stream>>>(T, Wkv, Wvo, out);
}

// Round 4
// 279.175 us; speedup vs baseline: 1.1546x; 1.1546x over previous
//
#include <hip/hip_runtime.h>
#include <math.h>

// Problem constants
#define LAM_INIT 0.2f
#define ONE_MINUS_LAM 0.8f
#define SCALING_F 0.05103103630798288f  // 384^-0.5

__device__ inline float waveMax(float v) {
#pragma unroll
    for (int o = 32; o > 0; o >>= 1) v = fmaxf(v, __shfl_xor(v, o));
    return v;
}
__device__ inline float waveMin(float v) {
#pragma unroll
    for (int o = 32; o > 0; o >>= 1) v = fminf(v, __shfl_xor(v, o));
    return v;
}
__device__ inline float waveSum(float v) {
#pragma unroll
    for (int o = 32; o > 0; o >>= 1) v += __shfl_xor(v, o);
    return v;
}

// ---------------------------------------------------------------------------
// K01: fused prep. 1281 blocks:
//  [0,128):   transpose key (B,L,32) -> keyT (B,32,L)
//  [128,512): Wcomb split-K x2
//  [512,1280): Wvo split-K x8
//  [1280]:    lam scalar
// Wcomb/Wvo accumulated with atomicAdd into pre-zeroed ws.
// ---------------------------------------------------------------------------
__global__ __launch_bounds__(256) void k01_prep(
    const float* __restrict__ key, const float* __restrict__ Wq,
    const float* __restrict__ Wkv, const float* __restrict__ Wout,
    const float* __restrict__ lq1, const float* __restrict__ lk1,
    const float* __restrict__ lq2, const float* __restrict__ lk2,
    const float* __restrict__ ln,
    float* __restrict__ keyT, float* __restrict__ Wcomb,
    float* __restrict__ Wvo, float* __restrict__ lam)
{
    int blk = blockIdx.x;
    int tid = threadIdx.x;
    if (blk < 128) {
        // --- transpose ---
        int b  = blk >> 4;
        int l0 = (blk & 15) << 8;
        __shared__ float tile[256 * 33];
        const float* kp = key + ((size_t)b * 4096 + l0) * 32;
#pragma unroll
        for (int q = 0; q < 32; ++q) {
            int idx = tid + (q << 8);
            int r = idx >> 5, g = idx & 31;
            tile[r * 33 + g] = kp[idx];
        }
        __syncthreads();
        float* op = keyT + (size_t)b * 32 * 4096 + l0;
#pragma unroll
        for (int q = 0; q < 32; ++q) {
            int idx = tid + (q << 8);
            int g = idx >> 8, ll = idx & 255;
            op[(size_t)g * 4096 + ll] = tile[ll * 33 + g];
        }
    } else if (blk < 512) {
        // --- Wcomb, split-K x2 ---
        int bb = blk - 128;          // 0..383
        int kc = bb & 1;
        int ob = bb >> 1;            // 0..191
        int idx = ob * 256 + tid;    // 0..49151
        int e  = idx >> 6;
        int hg = idx & 63;
        int h = hg >> 5, g = hg & 31;
        const float4* wqr = (const float4*)(Wq  + (size_t)e * 768 + h * 384 + kc * 192);
        const float4* wkr = (const float4*)(Wkv + (size_t)g * 1536 + h * 384 + kc * 192);
        float s0 = 0.f, s1 = 0.f;
#pragma unroll 4
        for (int d = 0; d < 48; d += 2) {
            float4 a0 = wqr[d],   b0 = wkr[d];
            float4 a1 = wqr[d+1], b1 = wkr[d+1];
            s0 += a0.x*b0.x + a0.y*b0.y + a0.z*b0.z + a0.w*b0.w;
            s1 += a1.x*b1.x + a1.y*b1.y + a1.z*b1.z + a1.w*b1.w;
        }
        atomicAdd(&Wcomb[idx], (s0 + s1) * SCALING_F);
    } else if (blk < 1280) {
        // --- Wvo, split-K x8 ---
        int bb = blk - 512;          // 0..767
        int kc = bb / 96;            // 0..7
        int ob = bb - kc * 96;       // 0..95
        int idx = ob * 256 + tid;    // 0..24575
        int g = idx / 768;
        int e = idx - g * 768;
        const float* wvr = Wkv + (size_t)g * 1536 + 768;
        int c0 = kc * 96;
        float s0 = 0.f, s1 = 0.f;
#pragma unroll 4
        for (int c = c0; c < c0 + 96; c += 2) {
            s0 += wvr[c]   * ln[c]   * Wout[(size_t)c * 768 + e];
            s1 += wvr[c+1] * ln[c+1] * Wout[(size_t)(c+1) * 768 + e];
        }
        atomicAdd(&Wvo[idx], s0 + s1);
    } else {
        // --- lambda ---
        float s1 = 0.f, s2 = 0.f;
        for (int d = tid; d < 384; d += 256) {
            s1 += lq1[d] * lk1[d];
            s2 += lq2[d] * lk2[d];
        }
        s1 = waveSum(s1);
        s2 = waveSum(s2);
        __shared__ float r1[4], r2[4];
        int wid = tid >> 6, lane = tid & 63;
        if (lane == 0) { r1[wid] = s1; r2[wid] = s2; }
        __syncthreads();
        if (tid == 0) {
            float a  = r1[0] + r1[1] + r1[2] + r1[3];
            float b2 = r2[0] + r2[1] + r2[2] + r2[3];
            lam[0] = expf(a) - expf(b2) + LAM_INIT;
        }
    }
}

// ---------------------------------------------------------------------------
// K2: Qt[m, n] = query[m, :768] @ Wcomb[:768, n]   (M=4096, N=64, K=768)
// 128 blocks, tile 32m x 64n, BK=32, thread = 2m x 4n.
// ---------------------------------------------------------------------------
__global__ __launch_bounds__(256) void k2_qt(
    const float* __restrict__ query, const float* __restrict__ Wcomb,
    float* __restrict__ Qt)
{
    int m0 = blockIdx.x * 32;
    int tid = threadIdx.x;
    int tx = tid & 15;       // col group: cols tx*4 .. +3
    int ty = tid >> 4;       // row group: rows ty*2 .. +1
    __shared__ __align__(16) float As[32 * 36];  // 32 rows x 32 k, pad 36
    __shared__ __align__(16) float Bs[32 * 64];  // 32 k x 64 n
    float acc[2][4] = {{0.f,0.f,0.f,0.f},{0.f,0.f,0.f,0.f}};

    for (int k0 = 0; k0 < 768; k0 += 32) {
        __syncthreads();
#pragma unroll
        for (int q = 0; q < 4; ++q) {
            int idx = tid + q * 256;       // 1024 elems
            int r = idx >> 5, c = idx & 31;
            As[r * 36 + c] = query[(size_t)(m0 + r) * 768 + k0 + c];
        }
#pragma unroll
        for (int q = 0; q < 8; ++q) {
            int idx = tid + q * 256;       // 2048 elems
            int r = idx >> 6, c = idx & 63;
            Bs[r * 64 + c] = Wcomb[(size_t)(k0 + r) * 64 + c];
        }
        __syncthreads();
#pragma unroll
        for (int kk = 0; kk < 32; kk += 4) {
            float4 a0 = *(const float4*)&As[(ty * 2 + 0) * 36 + kk];
            float4 a1 = *(const float4*)&As[(ty * 2 + 1) * 36 + kk];
            float4 b0 = *(const float4*)&Bs[(kk + 0) * 64 + tx * 4];
            float4 b1 = *(const float4*)&Bs[(kk + 1) * 64 + tx * 4];
            float4 b2 = *(const float4*)&Bs[(kk + 2) * 64 + tx * 4];
            float4 b3 = *(const float4*)&Bs[(kk + 3) * 64 + tx * 4];
            acc[0][0] += a0.x*b0.x + a0.y*b1.x + a0.z*b2.x + a0.w*b3.x;
            acc[0][1] += a0.x*b0.y + a0.y*b1.y + a0.z*b2.y + a0.w*b3.y;
            acc[0][2] += a0.x*b0.z + a0.y*b1.z + a0.z*b2.z + a0.w*b3.z;
            acc[0][3] += a0.x*b0.w + a0.y*b1.w + a0.z*b2.w + a0.w*b3.w;
            acc[1][0] += a1.x*b0.x + a1.y*b1.x + a1.z*b2.x + a1.w*b3.x;
            acc[1][1] += a1.x*b0.y + a1.y*b1.y + a1.z*b2.y + a1.w*b3.y;
            acc[1][2] += a1.x*b0.z + a1.y*b1.z + a1.z*b2.z + a1.w*b3.z;
            acc[1][3] += a1.x*b0.w + a1.y*b1.w + a1.z*b2.w + a1.w*b3.w;
        }
    }
#pragma unroll
    for (int rr = 0; rr < 2; ++rr) {
        float4 o; o.x = acc[rr][0]; o.y = acc[rr][1]; o.z = acc[rr][2]; o.w = acc[rr][3];
        *(float4*)&Qt[(size_t)(m0 + ty * 2 + rr) * 64 + tx * 4] = o;
    }
}

// ---------------------------------------------------------------------------
// K3 v4: fused scores -> masked softmax -> diff -> min-sub -> write.
// One block per (b, 4 s-rows). 1024 blocks x 512 threads (8 waves).
// Thread owns 8 l's (l = c*2048 + tid*4 + j, c<2): p[2][4][8] = 64 VGPR accs.
// qt transposed in LDS -> per-g broadcast is 2 ds_read_b128 (conflict-free).
// ---------------------------------------------------------------------------
__global__ __launch_bounds__(512, 4) void k3_attn(
    const float* __restrict__ Qt, const float* __restrict__ keyT,
    const int* __restrict__ qmask, const int* __restrict__ kmask,
    const float* __restrict__ lamp, float* __restrict__ diffO)
{
    int blk = blockIdx.x;
    int b  = blk >> 7;
    int s0 = (blk & 127) * 4;
    int tid = threadIdx.x;
    int lane = tid & 63, wid = tid >> 6;   // 8 waves

    __shared__ __align__(16) float qt_t[32 * 8];  // [g][(ts<<1)|h]
    __shared__ float red[64];                     // [(h*4+ts)*8 + wid]

    if (tid < 256) {
        int ts = tid >> 6, c2 = tid & 63;
        int h = c2 >> 5, g = c2 & 31;
        qt_t[g * 8 + (ts << 1) + h] = Qt[(size_t)(b * 512 + s0 + ts) * 64 + c2];
    }
    int qm[4];
#pragma unroll
    for (int ts = 0; ts < 4; ++ts) qm[ts] = qmask[b * 512 + s0 + ts];
    float lam = lamp[0];

    // kmask bits for the 8 owned l's
    unsigned kmb = 0;
#pragma unroll
    for (int c = 0; c < 2; ++c) {
        int4 km = *(const int4*)(kmask + b * 4096 + c * 2048 + tid * 4);
        if (km.x) kmb |= 1u << (c * 4 + 0);
        if (km.y) kmb |= 1u << (c * 4 + 1);
        if (km.z) kmb |= 1u << (c * 4 + 2);
        if (km.w) kmb |= 1u << (c * 4 + 3);
    }
    __syncthreads();

    float p[2][4][8];   // [h][ts][c*4+j]
#pragma unroll
    for (int h = 0; h < 2; ++h)
#pragma unroll
        for (int ts = 0; ts < 4; ++ts)
#pragma unroll
            for (int i = 0; i < 8; ++i) p[h][ts][i] = 0.f;

    const float* kt = keyT + (size_t)b * 131072 + tid * 4;
    for (int g = 0; g < 32; ++g) {
        float qv[8];
        *(float4*)&qv[0] = *(const float4*)&qt_t[g * 8];
        *(float4*)&qv[4] = *(const float4*)&qt_t[g * 8 + 4];
        const float* kg = kt + (size_t)g * 4096;
#pragma unroll
        for (int c = 0; c < 2; ++c) {
            float4 kv = *(const float4*)(kg + c * 2048);
#pragma unroll
            for (int ts = 0; ts < 4; ++ts)
#pragma unroll
                for (int h = 0; h < 2; ++h) {
                    float q = qv[ts * 2 + h];
                    p[h][ts][c*4+0] += q * kv.x;
                    p[h][ts][c*4+1] += q * kv.y;
                    p[h][ts][c*4+2] += q * kv.z;
                    p[h][ts][c*4+3] += q * kv.w;
                }
        }
    }

    // apply masks
#pragma unroll
    for (int h = 0; h < 2; ++h)
#pragma unroll
        for (int ts = 0; ts < 4; ++ts)
#pragma unroll
            for (int i = 0; i < 8; ++i) {
                bool ok = qm[ts] && ((kmb >> i) & 1u);
                p[h][ts][i] = ok ? p[h][ts][i] : -1e20f;
            }

    // Phase B1: row max (8 waves)
    float mrow[2][4];
#pragma unroll
    for (int h = 0; h < 2; ++h)
#pragma unroll
        for (int ts = 0; ts < 4; ++ts) {
            float v = -3.4e38f;
#pragma unroll
            for (int i = 0; i < 8; ++i) v = fmaxf(v, p[h][ts][i]);
            v = waveMax(v);
            if (lane == 0) red[(h * 4 + ts) * 8 + wid] = v;
        }
    __syncthreads();
#pragma unroll
    for (int h = 0; h < 2; ++h)
#pragma unroll
        for (int ts = 0; ts < 4; ++ts) {
            int r = (h * 4 + ts) * 8;
            float v = red[r];
#pragma unroll
            for (int w = 1; w < 8; ++w) v = fmaxf(v, red[r + w]);
            mrow[h][ts] = v;
        }
    __syncthreads();

    // Phase B2: exp + sum
    float inv[2][4];
#pragma unroll
    for (int h = 0; h < 2; ++h)
#pragma unroll
        for (int ts = 0; ts < 4; ++ts) {
            float s = 0.f;
#pragma unroll
            for (int i = 0; i < 8; ++i) {
                float e2 = __expf(p[h][ts][i] - mrow[h][ts]);
                p[h][ts][i] = e2;
                s += e2;
            }
            s = waveSum(s);
            if (lane == 0) red[(h * 4 + ts) * 8 + wid] = s;
        }
    __syncthreads();
#pragma unroll
    for (int h = 0; h < 2; ++h)
#pragma unroll
        for (int ts = 0; ts < 4; ++ts) {
            int r = (h * 4 + ts) * 8;
            float s = red[r];
#pragma unroll
            for (int w = 1; w < 8; ++w) s += red[r + w];
            inv[h][ts] = 1.0f / (s + 1e-8f);
        }
    __syncthreads();

    // Phase C: diff + min (d stored over p[0][ts][i])
    float mn[4];
#pragma unroll
    for (int ts = 0; ts < 4; ++ts) {
        float v = 3.4e38f;
#pragma unroll
        for (int i = 0; i < 8; ++i) {
            float d = p[0][ts][i] * inv[0][ts] - lam * (p[1][ts][i] * inv[1][ts]);
            p[0][ts][i] = d;
            v = fminf(v, d);
        }
        v = waveMin(v);
        if (lane == 0) red[ts * 8 + wid] = v;
    }
    __syncthreads();
#pragma unroll
    for (int ts = 0; ts < 4; ++ts) {
        int r = ts * 8;
        float v = red[r];
#pragma unroll
        for (int w = 1; w < 8; ++w) v = fminf(v, red[r + w]);
        mn[ts] = v;
    }

    // Phase D: write diff output (float4, coalesced)
#pragma unroll
    for (int ts = 0; ts < 4; ++ts) {
        size_t base = (size_t)(b * 512 + s0 + ts) * 4096 + tid * 4;
#pragma unroll
        for (int c = 0; c < 2; ++c) {
            float4 o;
            float v0 = p[0][ts][c*4+0] - mn[ts] + 1e-20f;
            float v1 = p[0][ts][c*4+1] - mn[ts] + 1e-20f;
            float v2 = p[0][ts][c*4+2] - mn[ts] + 1e-20f;
            float v3 = p[0][ts][c*4+3] - mn[ts] + 1e-20f;
            o.x = (qm[ts] && ((kmb >> (c*4+0)) & 1u)) ? v0 : 0.f;
            o.y = (qm[ts] && ((kmb >> (c*4+1)) & 1u)) ? v1 : 0.f;
            o.z = (qm[ts] && ((kmb >> (c*4+2)) & 1u)) ? v2 : 0.f;
            o.w = (qm[ts] && ((kmb >> (c*4+3)) & 1u)) ? v3 : 0.f;
            *(float4*)(diffO + base + c * 2048) = o;
        }
    }
}

// ---------------------------------------------------------------------------
// K4: T[row, g] = sum_l diff[row, l] * key[b, l, g]   (rows=4096, g=32, K=4096)
// 512 blocks = 32 row-tiles(128) x 16 k-chunks(256). key tile in LDS,
// diff via vectorized global (L2/L3-resident). atomicAdd epilogue (T pre-zeroed).
// ---------------------------------------------------------------------------
__global__ __launch_bounds__(256) void k4_T(
    const float* __restrict__ diff, const float* __restrict__ key,
    float* __restrict__ T)
{
    int blk = blockIdx.x;
    int rt = blk & 31, kc = blk >> 5;
    int row0 = rt << 7;     // *128
    int b = row0 >> 9;
    int l0 = kc << 8;       // *256
    int tid = threadIdx.x;
    int tx = tid & 7;       // g0 = tx*4
    int ty = tid >> 3;      // rows row0 + ty*4 + r
    int g0 = tx * 4;

    __shared__ __align__(16) float Ks[256][32];
#pragma unroll
    for (int q = 0; q < 32; ++q) {
        int idx = tid + (q << 8);
        int r = idx >> 5, g = idx & 31;
        Ks[r][g] = key[((size_t)(b * 4096 + l0 + r)) * 32 + g];
    }
    __syncthreads();

    float acc[4][4];
#pragma unroll
    for (int r = 0; r < 4; ++r)
#pragma unroll
        for (int c2 = 0; c2 < 4; ++c2) acc[r][c2] = 0.f;

    for (int j4 = 0; j4 < 64; ++j4) {
        int l = l0 + j4 * 4;
        float4 dv[4];
#pragma unroll
        for (int r = 0; r < 4; ++r)
            dv[r] = *(const float4*)(diff + (size_t)(row0 + ty * 4 + r) * 4096 + l);
#pragma unroll
        for (int jj = 0; jj < 4; ++jj) {
            float4 kq = *(const float4*)&Ks[j4 * 4 + jj][g0];
#pragma unroll
            for (int r = 0; r < 4; ++r) {
                float d = (jj == 0) ? dv[r].x : (jj == 1) ? dv[r].y : (jj == 2) ? dv[r].z : dv[r].w;
                acc[r][0] += d * kq.x;
                acc[r][1] += d * kq.y;
                acc[r][2] += d * kq.z;
                acc[r][3] += d * kq.w;
            }
        }
    }
#pragma unroll
    for (int r = 0; r < 4; ++r)
#pragma unroll
        for (int c2 = 0; c2 < 4; ++c2)
            atomicAdd(&T[(size_t)(row0 + ty * 4 + r) * 32 + g0 + c2], acc[r][c2]);
}

// ---------------------------------------------------------------------------
// K5: per-row RMS statistic from a = T@Wv, then out = 0.8*rs * (T @ Wvo)
// 512 blocks x 8 rows. Thread owns 3 e-columns.
// ---------------------------------------------------------------------------
__global__ __launch_bounds__(256) void k5_out(
    const float* __restrict__ T, const float* __restrict__ Wkv,
    const float* __restrict__ Wvo, float* __restrict__ out)
{
    int row0 = blockIdx.x * 8;
    int tid = threadIdx.x;
    int wid = tid >> 6, lane = tid & 63;
    __shared__ __align__(16) float Ts[8][32];
    __shared__ float red[8][4];
    __shared__ float rs_s[8];

    {
        int r = tid >> 5, g = tid & 31;
        Ts[r][g] = T[(size_t)(row0 + r) * 32 + g];
    }
    __syncthreads();

    float ssq[8];
#pragma unroll
    for (int r = 0; r < 8; ++r) ssq[r] = 0.f;

#pragma unroll
    for (int ec = 0; ec < 3; ++ec) {
        int e = tid + ec * 256;
        float wv[32];
#pragma unroll
        for (int g = 0; g < 32; ++g) wv[g] = Wkv[(size_t)g * 1536 + 768 + e];
#pragma unroll
        for (int r = 0; r < 8; ++r) {
            float a = 0.f;
#pragma unroll
            for (int g = 0; g < 32; ++g) a += Ts[r][g] * wv[g];
            ssq[r] += a * a;
        }
    }
#pragma unroll
    for (int r = 0; r < 8; ++r) {
        float v = waveSum(ssq[r]);
        if (lane == 0) red[r][wid] = v;
    }
    __syncthreads();
    if (tid < 8) {
        float s = red[tid][0] + red[tid][1] + red[tid][2] + red[tid][3];
        float ms = s * (1.0f / 768.0f);
        rs_s[tid] = rsqrtf(ms + 1e-5f) * ONE_MINUS_LAM;
    }
    __syncthreads();

#pragma unroll
    for (int ec = 0; ec < 3; ++ec) {
        int e = tid + ec * 256;
        float wo[32];
#pragma unroll
        for (int g = 0; g < 32; ++g) wo[g] = Wvo[(size_t)g * 768 + e];
#pragma unroll
        for (int r = 0; r < 8; ++r) {
            float o = 0.f;
#pragma unroll
            for (int g = 0; g < 32; ++g) o += Ts[r][g] * wo[g];
            out[(size_t)(row0 + r) * 768 + e] = o * rs_s[r];
        }
    }
}

// ---------------------------------------------------------------------------
extern "C" void kernel_launch(void* const* d_in, const int* in_sizes, int n_in,
                              void* d_out, int out_size, void* d_ws, size_t ws_size,
                              hipStream_t stream) {
    (void)in_sizes; (void)n_in; (void)out_size; (void)ws_size;
    const float* query = (const float*)d_in[0];
    const float* key   = (const float*)d_in[1];
    const int*   qmask = (const int*)d_in[2];
    const int*   kmask = (const int*)d_in[3];
    const float* Wq    = (const float*)d_in[4];
    const float* Wkv   = (const float*)d_in[5];
    const float* Wout  = (const float*)d_in[6];
    const float* lq1   = (const float*)d_in[7];
    const float* lk1   = (const float*)d_in[8];
    const float* lq2   = (const float*)d_in[9];
    const float* lk2   = (const float*)d_in[10];
    const float* ln    = (const float*)d_in[11];

    float* out  = (float*)d_out;          // (B,S,E) = 3,145,728 floats
    float* diff = out + 3145728;          // (B,S,L) = 16,777,216 floats

    float* ws    = (float*)d_ws;
    float* Wcomb = ws;                    // 49152   (zeroed)
    float* Wvo   = ws + 49152;            // 24576   (zeroed)
    float* T     = ws + 73728;            // 131072  (zeroed)
    float* lam   = ws + 204800;           // 64
    float* Qt    = ws + 204864;           // 262144
    float* keyT  = ws + 467008;           // 1048576  -> total ~6.1 MB

    hipMemsetAsync(ws, 0, 204800 * sizeof(float), stream);
    k01_prep<<<1281, 256, 0, stream>>>(key, Wq, Wkv, Wout, lq1, lk1, lq2, lk2, ln,
                                       keyT, Wcomb, Wvo, lam);
    k2_qt<<<128, 256, 0, stream>>>(query, Wcomb, Qt);
    k3_attn<<<1024, 512, 0, stream>>>(Qt, keyT, qmask, kmask, lam, diff);
    k4_T<<<512, 256, 0, stream>>>(diff, key, T);
    k5_out<<<512, 256, 0, stream>>>(T, Wkv, Wvo, out);
}

// Round 5
// 269.260 us; speedup vs baseline: 1.1971x; 1.0368x over previous
//
#include <hip/hip_runtime.h>
#include <math.h>

// Problem constants
#define LAM_INIT 0.2f
#define ONE_MINUS_LAM 0.8f
#define SCALING_F 0.05103103630798288f  // 384^-0.5

__device__ inline float waveMax(float v) {
#pragma unroll
    for (int o = 32; o > 0; o >>= 1) v = fmaxf(v, __shfl_xor(v, o));
    return v;
}
__device__ inline float waveMin(float v) {
#pragma unroll
    for (int o = 32; o > 0; o >>= 1) v = fminf(v, __shfl_xor(v, o));
    return v;
}
__device__ inline float waveSum(float v) {
#pragma unroll
    for (int o = 32; o > 0; o >>= 1) v += __shfl_xor(v, o);
    return v;
}

// ---------------------------------------------------------------------------
// K01: fused prep. 1281 blocks:
//  [0,128):   transpose key (B,L,32) -> keyT (B,32,L)
//  [128,512): Wcomb split-K x2 (atomicAdd, 2-way contention only; pre-zeroed)
//  [512,1280): Wvo split-K x8 -> partials Wvp[kc] (direct store, NO atomics)
//  [1280]:    lam scalar
// ---------------------------------------------------------------------------
__global__ __launch_bounds__(256) void k01_prep(
    const float* __restrict__ key, const float* __restrict__ Wq,
    const float* __restrict__ Wkv, const float* __restrict__ Wout,
    const float* __restrict__ lq1, const float* __restrict__ lk1,
    const float* __restrict__ lq2, const float* __restrict__ lk2,
    const float* __restrict__ ln,
    float* __restrict__ keyT, float* __restrict__ Wcomb,
    float* __restrict__ Wvp, float* __restrict__ lam)
{
    int blk = blockIdx.x;
    int tid = threadIdx.x;
    if (blk < 128) {
        // --- transpose ---
        int b  = blk >> 4;
        int l0 = (blk & 15) << 8;
        __shared__ float tile[256 * 33];
        const float* kp = key + ((size_t)b * 4096 + l0) * 32;
#pragma unroll
        for (int q = 0; q < 32; ++q) {
            int idx = tid + (q << 8);
            int r = idx >> 5, g = idx & 31;
            tile[r * 33 + g] = kp[idx];
        }
        __syncthreads();
        float* op = keyT + (size_t)b * 32 * 4096 + l0;
#pragma unroll
        for (int q = 0; q < 32; ++q) {
            int idx = tid + (q << 8);
            int g = idx >> 8, ll = idx & 255;
            op[(size_t)g * 4096 + ll] = tile[ll * 33 + g];
        }
    } else if (blk < 512) {
        // --- Wcomb, split-K x2 ---
        int bb = blk - 128;          // 0..383
        int kc = bb & 1;
        int ob = bb >> 1;            // 0..191
        int idx = ob * 256 + tid;    // 0..49151
        int e  = idx >> 6;
        int hg = idx & 63;
        int h = hg >> 5, g = hg & 31;
        const float4* wqr = (const float4*)(Wq  + (size_t)e * 768 + h * 384 + kc * 192);
        const float4* wkr = (const float4*)(Wkv + (size_t)g * 1536 + h * 384 + kc * 192);
        float s0 = 0.f, s1 = 0.f;
#pragma unroll 4
        for (int d = 0; d < 48; d += 2) {
            float4 a0 = wqr[d],   b0 = wkr[d];
            float4 a1 = wqr[d+1], b1 = wkr[d+1];
            s0 += a0.x*b0.x + a0.y*b0.y + a0.z*b0.z + a0.w*b0.w;
            s1 += a1.x*b1.x + a1.y*b1.y + a1.z*b1.z + a1.w*b1.w;
        }
        atomicAdd(&Wcomb[idx], (s0 + s1) * SCALING_F);
    } else if (blk < 1280) {
        // --- Wvo partials, split-K x8, direct store ---
        int bb = blk - 512;          // 0..767
        int kc = bb / 96;            // 0..7
        int ob = bb - kc * 96;       // 0..95
        int idx = ob * 256 + tid;    // 0..24575
        int g = idx / 768;
        int e = idx - g * 768;
        const float* wvr = Wkv + (size_t)g * 1536 + 768;
        int c0 = kc * 96;
        float s0 = 0.f, s1 = 0.f;
#pragma unroll 4
        for (int c = c0; c < c0 + 96; c += 2) {
            s0 += wvr[c]   * ln[c]   * Wout[(size_t)c * 768 + e];
            s1 += wvr[c+1] * ln[c+1] * Wout[(size_t)(c+1) * 768 + e];
        }
        Wvp[kc * 24576 + idx] = s0 + s1;
    } else {
        // --- lambda ---
        float s1 = 0.f, s2 = 0.f;
        for (int d = tid; d < 384; d += 256) {
            s1 += lq1[d] * lk1[d];
            s2 += lq2[d] * lk2[d];
        }
        s1 = waveSum(s1);
        s2 = waveSum(s2);
        __shared__ float r1[4], r2[4];
        int wid = tid >> 6, lane = tid & 63;
        if (lane == 0) { r1[wid] = s1; r2[wid] = s2; }
        __syncthreads();
        if (tid == 0) {
            float a  = r1[0] + r1[1] + r1[2] + r1[3];
            float b2 = r2[0] + r2[1] + r2[2] + r2[3];
            lam[0] = expf(a) - expf(b2) + LAM_INIT;
        }
    }
}

// ---------------------------------------------------------------------------
// K2 v2: Qt[m, n] = query[m, :768] @ Wcomb[:768, n]
// Blocks [0,256): m-tile 16 rows in LDS (stride 772, conflict-light);
//   thread = (m_local = tid>>4, n-quad = (tid&15)*4); K=768 dot with
//   Wcomb float4 straight from L2 (196 KB resident, broadcast across waves).
// Blocks [256,352): reduce Wvo = sum of 8 Wvp partials.
// ---------------------------------------------------------------------------
__global__ __launch_bounds__(256) void k2_qt(
    const float* __restrict__ query, const float* __restrict__ Wcomb,
    const float* __restrict__ Wvp, float* __restrict__ Wvo,
    float* __restrict__ Qt)
{
    int blk = blockIdx.x;
    int tid = threadIdx.x;
    if (blk >= 256) {
        int idx = (blk - 256) * 256 + tid;   // 0..24575
        float s = 0.f;
#pragma unroll
        for (int kc = 0; kc < 8; ++kc) s += Wvp[kc * 24576 + idx];
        Wvo[idx] = s;
        return;
    }
    int m0 = blk * 16;
    __shared__ __align__(16) float Aq[16 * 772];
#pragma unroll
    for (int q = 0; q < 12; ++q) {
        int f = tid + q * 256;          // 0..3071 float4s
        int r = f / 192, c4 = f - r * 192;
        float4 v = *(const float4*)&query[(size_t)(m0 + r) * 768 + c4 * 4];
        *(float4*)&Aq[r * 772 + c4 * 4] = v;
    }
    __syncthreads();

    int n0 = (tid & 15) * 4;
    int ml = tid >> 4;
    const float* arow = &Aq[ml * 772];
    float ax = 0.f, ay = 0.f, az = 0.f, aw = 0.f;
    for (int k = 0; k < 768; k += 8) {
#pragma unroll
        for (int j = 0; j < 8; ++j) {
            float a = arow[k + j];
            float4 w = *(const float4*)&Wcomb[(size_t)(k + j) * 64 + n0];
            ax += a * w.x; ay += a * w.y; az += a * w.z; aw += a * w.w;
        }
    }
    float4 o; o.x = ax; o.y = ay; o.z = az; o.w = aw;
    *(float4*)&Qt[(size_t)(m0 + ml) * 64 + n0] = o;
}

// ---------------------------------------------------------------------------
// K3 v4 (unchanged from R4): fused scores -> masked softmax -> diff -> min-sub.
// 1024 blocks x 512 threads; thread owns 8 l's; p[2][4][8] in regs.
// ---------------------------------------------------------------------------
__global__ __launch_bounds__(512, 4) void k3_attn(
    const float* __restrict__ Qt, const float* __restrict__ keyT,
    const int* __restrict__ qmask, const int* __restrict__ kmask,
    const float* __restrict__ lamp, float* __restrict__ diffO)
{
    int blk = blockIdx.x;
    int b  = blk >> 7;
    int s0 = (blk & 127) * 4;
    int tid = threadIdx.x;
    int lane = tid & 63, wid = tid >> 6;   // 8 waves

    __shared__ __align__(16) float qt_t[32 * 8];  // [g][(ts<<1)|h]
    __shared__ float red[64];

    if (tid < 256) {
        int ts = tid >> 6, c2 = tid & 63;
        int h = c2 >> 5, g = c2 & 31;
        qt_t[g * 8 + (ts << 1) + h] = Qt[(size_t)(b * 512 + s0 + ts) * 64 + c2];
    }
    int qm[4];
#pragma unroll
    for (int ts = 0; ts < 4; ++ts) qm[ts] = qmask[b * 512 + s0 + ts];
    float lam = lamp[0];

    unsigned kmb = 0;
#pragma unroll
    for (int c = 0; c < 2; ++c) {
        int4 km = *(const int4*)(kmask + b * 4096 + c * 2048 + tid * 4);
        if (km.x) kmb |= 1u << (c * 4 + 0);
        if (km.y) kmb |= 1u << (c * 4 + 1);
        if (km.z) kmb |= 1u << (c * 4 + 2);
        if (km.w) kmb |= 1u << (c * 4 + 3);
    }
    __syncthreads();

    float p[2][4][8];
#pragma unroll
    for (int h = 0; h < 2; ++h)
#pragma unroll
        for (int ts = 0; ts < 4; ++ts)
#pragma unroll
            for (int i = 0; i < 8; ++i) p[h][ts][i] = 0.f;

    const float* kt = keyT + (size_t)b * 131072 + tid * 4;
    for (int g = 0; g < 32; ++g) {
        float qv[8];
        *(float4*)&qv[0] = *(const float4*)&qt_t[g * 8];
        *(float4*)&qv[4] = *(const float4*)&qt_t[g * 8 + 4];
        const float* kg = kt + (size_t)g * 4096;
#pragma unroll
        for (int c = 0; c < 2; ++c) {
            float4 kv = *(const float4*)(kg + c * 2048);
#pragma unroll
            for (int ts = 0; ts < 4; ++ts)
#pragma unroll
                for (int h = 0; h < 2; ++h) {
                    float q = qv[ts * 2 + h];
                    p[h][ts][c*4+0] += q * kv.x;
                    p[h][ts][c*4+1] += q * kv.y;
                    p[h][ts][c*4+2] += q * kv.z;
                    p[h][ts][c*4+3] += q * kv.w;
                }
        }
    }

#pragma unroll
    for (int h = 0; h < 2; ++h)
#pragma unroll
        for (int ts = 0; ts < 4; ++ts)
#pragma unroll
            for (int i = 0; i < 8; ++i) {
                bool ok = qm[ts] && ((kmb >> i) & 1u);
                p[h][ts][i] = ok ? p[h][ts][i] : -1e20f;
            }

    float mrow[2][4];
#pragma unroll
    for (int h = 0; h < 2; ++h)
#pragma unroll
        for (int ts = 0; ts < 4; ++ts) {
            float v = -3.4e38f;
#pragma unroll
            for (int i = 0; i < 8; ++i) v = fmaxf(v, p[h][ts][i]);
            v = waveMax(v);
            if (lane == 0) red[(h * 4 + ts) * 8 + wid] = v;
        }
    __syncthreads();
#pragma unroll
    for (int h = 0; h < 2; ++h)
#pragma unroll
        for (int ts = 0; ts < 4; ++ts) {
            int r = (h * 4 + ts) * 8;
            float v = red[r];
#pragma unroll
            for (int w = 1; w < 8; ++w) v = fmaxf(v, red[r + w]);
            mrow[h][ts] = v;
        }
    __syncthreads();

    float inv[2][4];
#pragma unroll
    for (int h = 0; h < 2; ++h)
#pragma unroll
        for (int ts = 0; ts < 4; ++ts) {
            float s = 0.f;
#pragma unroll
            for (int i = 0; i < 8; ++i) {
                float e2 = __expf(p[h][ts][i] - mrow[h][ts]);
                p[h][ts][i] = e2;
                s += e2;
            }
            s = waveSum(s);
            if (lane == 0) red[(h * 4 + ts) * 8 + wid] = s;
        }
    __syncthreads();
#pragma unroll
    for (int h = 0; h < 2; ++h)
#pragma unroll
        for (int ts = 0; ts < 4; ++ts) {
            int r = (h * 4 + ts) * 8;
            float s = red[r];
#pragma unroll
            for (int w = 1; w < 8; ++w) s += red[r + w];
            inv[h][ts] = 1.0f / (s + 1e-8f);
        }
    __syncthreads();

    float mn[4];
#pragma unroll
    for (int ts = 0; ts < 4; ++ts) {
        float v = 3.4e38f;
#pragma unroll
        for (int i = 0; i < 8; ++i) {
            float d = p[0][ts][i] * inv[0][ts] - lam * (p[1][ts][i] * inv[1][ts]);
            p[0][ts][i] = d;
            v = fminf(v, d);
        }
        v = waveMin(v);
        if (lane == 0) red[ts * 8 + wid] = v;
    }
    __syncthreads();
#pragma unroll
    for (int ts = 0; ts < 4; ++ts) {
        int r = ts * 8;
        float v = red[r];
#pragma unroll
        for (int w = 1; w < 8; ++w) v = fminf(v, red[r + w]);
        mn[ts] = v;
    }

#pragma unroll
    for (int ts = 0; ts < 4; ++ts) {
        size_t base = (size_t)(b * 512 + s0 + ts) * 4096 + tid * 4;
#pragma unroll
        for (int c = 0; c < 2; ++c) {
            float4 o;
            float v0 = p[0][ts][c*4+0] - mn[ts] + 1e-20f;
            float v1 = p[0][ts][c*4+1] - mn[ts] + 1e-20f;
            float v2 = p[0][ts][c*4+2] - mn[ts] + 1e-20f;
            float v3 = p[0][ts][c*4+3] - mn[ts] + 1e-20f;
            o.x = (qm[ts] && ((kmb >> (c*4+0)) & 1u)) ? v0 : 0.f;
            o.y = (qm[ts] && ((kmb >> (c*4+1)) & 1u)) ? v1 : 0.f;
            o.z = (qm[ts] && ((kmb >> (c*4+2)) & 1u)) ? v2 : 0.f;
            o.w = (qm[ts] && ((kmb >> (c*4+3)) & 1u)) ? v3 : 0.f;
            *(float4*)(diffO + base + c * 2048) = o;
        }
    }
}

// ---------------------------------------------------------------------------
// K4 v2: T partials. P[kc][row][g] = sum_{l in chunk kc} diff[row,l]*key[b,l,g]
// 256 blocks = 32 row-tiles(128) x 8 k-chunks(512 l, two 256-l LDS phases).
// Direct stores to P — NO atomics.
// ---------------------------------------------------------------------------
__global__ __launch_bounds__(256) void k4_T(
    const float* __restrict__ diff, const float* __restrict__ key,
    float* __restrict__ P)
{
    int blk = blockIdx.x;
    int rt = blk & 31, kc = blk >> 5;   // rt<32, kc<8
    int row0 = rt << 7;     // *128
    int b = row0 >> 9;
    int l0 = kc << 9;       // *512
    int tid = threadIdx.x;
    int tx = tid & 7;       // g0 = tx*4
    int ty = tid >> 3;      // rows row0 + ty*4 + r
    int g0 = tx * 4;

    __shared__ __align__(16) float Ks[256][32];

    float acc[4][4];
#pragma unroll
    for (int r = 0; r < 4; ++r)
#pragma unroll
        for (int c2 = 0; c2 < 4; ++c2) acc[r][c2] = 0.f;

    for (int ph = 0; ph < 2; ++ph) {
        int lp = l0 + ph * 256;
        __syncthreads();
#pragma unroll
        for (int q = 0; q < 32; ++q) {
            int idx = tid + (q << 8);
            int r = idx >> 5, g = idx & 31;
            Ks[r][g] = key[((size_t)(b * 4096 + lp + r)) * 32 + g];
        }
        __syncthreads();

        for (int j4 = 0; j4 < 64; ++j4) {
            int l = lp + j4 * 4;
            float4 dv[4];
#pragma unroll
            for (int r = 0; r < 4; ++r)
                dv[r] = *(const float4*)(diff + (size_t)(row0 + ty * 4 + r) * 4096 + l);
#pragma unroll
            for (int jj = 0; jj < 4; ++jj) {
                float4 kq = *(const float4*)&Ks[j4 * 4 + jj][g0];
#pragma unroll
                for (int r = 0; r < 4; ++r) {
                    float d = (jj == 0) ? dv[r].x : (jj == 1) ? dv[r].y : (jj == 2) ? dv[r].z : dv[r].w;
                    acc[r][0] += d * kq.x;
                    acc[r][1] += d * kq.y;
                    acc[r][2] += d * kq.z;
                    acc[r][3] += d * kq.w;
                }
            }
        }
    }
#pragma unroll
    for (int r = 0; r < 4; ++r) {
        float4 o; o.x = acc[r][0]; o.y = acc[r][1]; o.z = acc[r][2]; o.w = acc[r][3];
        *(float4*)&P[(size_t)kc * 131072 + (size_t)(row0 + ty * 4 + r) * 32 + g0] = o;
    }
}

// ---------------------------------------------------------------------------
// K5 v2: reduce T = sum_kc P[kc], then RMS statistic from a = T@Wv, then
// out = 0.8*rs * (T @ Wvo). 512 blocks x 8 rows.
// ---------------------------------------------------------------------------
__global__ __launch_bounds__(256) void k5_out(
    const float* __restrict__ P, const float* __restrict__ Wkv,
    const float* __restrict__ Wvo, float* __restrict__ out)
{
    int row0 = blockIdx.x * 8;
    int tid = threadIdx.x;
    int wid = tid >> 6, lane = tid & 63;
    __shared__ __align__(16) float Ts[8][32];
    __shared__ float red[8][4];
    __shared__ float rs_s[8];

    {
        int r = tid >> 5, g = tid & 31;
        float s = 0.f;
#pragma unroll
        for (int kc = 0; kc < 8; ++kc)
            s += P[(size_t)kc * 131072 + (size_t)(row0 + r) * 32 + g];
        Ts[r][g] = s;
    }
    __syncthreads();

    float ssq[8];
#pragma unroll
    for (int r = 0; r < 8; ++r) ssq[r] = 0.f;

#pragma unroll
    for (int ec = 0; ec < 3; ++ec) {
        int e = tid + ec * 256;
        float wv[32];
#pragma unroll
        for (int g = 0; g < 32; ++g) wv[g] = Wkv[(size_t)g * 1536 + 768 + e];
#pragma unroll
        for (int r = 0; r < 8; ++r) {
            float a = 0.f;
#pragma unroll
            for (int g = 0; g < 32; ++g) a += Ts[r][g] * wv[g];
            ssq[r] += a * a;
        }
    }
#pragma unroll
    for (int r = 0; r < 8; ++r) {
        float v = waveSum(ssq[r]);
        if (lane == 0) red[r][wid] = v;
    }
    __syncthreads();
    if (tid < 8) {
        float s = red[tid][0] + red[tid][1] + red[tid][2] + red[tid][3];
        float ms = s * (1.0f / 768.0f);
        rs_s[tid] = rsqrtf(ms + 1e-5f) * ONE_MINUS_LAM;
    }
    __syncthreads();

#pragma unroll
    for (int ec = 0; ec < 3; ++ec) {
        int e = tid + ec * 256;
        float wo[32];
#pragma unroll
        for (int g = 0; g < 32; ++g) wo[g] = Wvo[(size_t)g * 768 + e];
#pragma unroll
        for (int r = 0; r < 8; ++r) {
            float o = 0.f;
#pragma unroll
            for (int g = 0; g < 32; ++g) o += Ts[r][g] * wo[g];
            out[(size_t)(row0 + r) * 768 + e] = o * rs_s[r];
        }
    }
}

// ---------------------------------------------------------------------------
extern "C" void kernel_launch(void* const* d_in, const int* in_sizes, int n_in,
                              void* d_out, int out_size, void* d_ws, size_t ws_size,
                              hipStream_t stream) {
    (void)in_sizes; (void)n_in; (void)out_size; (void)ws_size;
    const float* query = (const float*)d_in[0];
    const float* key   = (const float*)d_in[1];
    const int*   qmask = (const int*)d_in[2];
    const int*   kmask = (const int*)d_in[3];
    const float* Wq    = (const float*)d_in[4];
    const float* Wkv   = (const float*)d_in[5];
    const float* Wout  = (const float*)d_in[6];
    const float* lq1   = (const float*)d_in[7];
    const float* lk1   = (const float*)d_in[8];
    const float* lq2   = (const float*)d_in[9];
    const float* lk2   = (const float*)d_in[10];
    const float* ln    = (const float*)d_in[11];

    float* out  = (float*)d_out;          // (B,S,E) = 3,145,728 floats
    float* diff = out + 3145728;          // (B,S,L) = 16,777,216 floats

    float* ws    = (float*)d_ws;
    float* Wcomb = ws;                    // 49152   (zeroed; x2 atomics)
    float* Wvo   = ws + 49152;            // 24576   (written by k2 reduce branch)
    float* Wvp   = ws + 73728;            // 196608  (8 partials, direct store)
    float* lam   = ws + 270336;           // 64
    float* Qt    = ws + 270400;           // 262144
    float* keyT  = ws + 532544;           // 1048576
    float* P     = ws + 1581120;          // 1048576 (8 T-partials)
                                          // total ~10.0 MB

    hipMemsetAsync(Wcomb, 0, 49152 * sizeof(float), stream);
    k01_prep<<<1281, 256, 0, stream>>>(key, Wq, Wkv, Wout, lq1, lk1, lq2, lk2, ln,
                                       keyT, Wcomb, Wvp, lam);
    k2_qt<<<352, 256, 0, stream>>>(query, Wcomb, Wvp, Wvo, Qt);
    k3_attn<<<1024, 512, 0, stream>>>(Qt, keyT, qmask, kmask, lam, diff);
    k4_T<<<256, 256, 0, stream>>>(diff, key, P);
    k5_out<<<512, 256, 0, stream>>>(P, Wkv, Wvo, out);
}

// Round 6
// 236.018 us; speedup vs baseline: 1.3657x; 1.1408x over previous
//
#include <hip/hip_runtime.h>
#include <math.h>

#define LAM_INIT 0.2f
#define ONE_MINUS_LAM 0.8f
#define SCALING_F 0.05103103630798288f  // 384^-0.5

typedef _Float16 h2 __attribute__((ext_vector_type(2)));

#if defined(__has_builtin)
#if __has_builtin(__builtin_amdgcn_fdot2)
#define FDOT2(a, b, c) __builtin_amdgcn_fdot2((a), (b), (c), false)
#endif
#endif
#ifndef FDOT2
#define FDOT2(a, b, c) ((float)(a).x * (float)(b).x + ((float)(a).y * (float)(b).y + (c)))
#endif

__device__ inline float waveMax(float v) {
#pragma unroll
    for (int o = 32; o > 0; o >>= 1) v = fmaxf(v, __shfl_xor(v, o));
    return v;
}
__device__ inline float waveMin(float v) {
#pragma unroll
    for (int o = 32; o > 0; o >>= 1) v = fminf(v, __shfl_xor(v, o));
    return v;
}
__device__ inline float waveSum(float v) {
#pragma unroll
    for (int o = 32; o > 0; o >>= 1) v += __shfl_xor(v, o);
    return v;
}

// ---------------------------------------------------------------------------
// K01: fused prep. 1281 blocks:
//  [0,128):   transpose key (B,L,32) -> keyTh packed half2 [b][gpair][l]
//  [128,512): Wcomb split-K x2 -> Wcp[kc] partials (direct store, no atomics)
//  [512,1280): Wvo split-K x8 -> Wvp[kc] partials (direct store)
//  [1280]:    lam scalar
// ---------------------------------------------------------------------------
__global__ __launch_bounds__(256) void k01_prep(
    const float* __restrict__ key, const float* __restrict__ Wq,
    const float* __restrict__ Wkv, const float* __restrict__ Wout,
    const float* __restrict__ lq1, const float* __restrict__ lk1,
    const float* __restrict__ lq2, const float* __restrict__ lk2,
    const float* __restrict__ ln,
    unsigned* __restrict__ keyThU, float* __restrict__ Wcp,
    float* __restrict__ Wvp, float* __restrict__ lam)
{
    int blk = blockIdx.x;
    int tid = threadIdx.x;
    if (blk < 128) {
        // --- transpose + fp16 pack ---
        int b  = blk >> 4;
        int l0 = (blk & 15) << 8;
        __shared__ float tile[256 * 33];
        const float* kp = key + ((size_t)b * 4096 + l0) * 32;
#pragma unroll
        for (int q = 0; q < 32; ++q) {
            int idx = tid + (q << 8);
            int r = idx >> 5, g = idx & 31;
            tile[r * 33 + g] = kp[idx];
        }
        __syncthreads();
#pragma unroll
        for (int gp = 0; gp < 16; ++gp) {
            h2 v;
            v.x = (_Float16)tile[tid * 33 + 2 * gp];
            v.y = (_Float16)tile[tid * 33 + 2 * gp + 1];
            keyThU[((size_t)(b * 16 + gp)) * 4096 + l0 + tid] =
                __builtin_bit_cast(unsigned, v);
        }
    } else if (blk < 512) {
        // --- Wcomb partials, split-K x2 ---
        int bb = blk - 128;
        int kc = bb & 1;
        int ob = bb >> 1;            // 0..191
        int idx = ob * 256 + tid;    // 0..49151
        int e  = idx >> 6;
        int hg = idx & 63;
        int h = hg >> 5, g = hg & 31;
        const float4* wqr = (const float4*)(Wq  + (size_t)e * 768 + h * 384 + kc * 192);
        const float4* wkr = (const float4*)(Wkv + (size_t)g * 1536 + h * 384 + kc * 192);
        float s0 = 0.f, s1 = 0.f;
#pragma unroll 4
        for (int d = 0; d < 48; d += 2) {
            float4 a0 = wqr[d],   b0 = wkr[d];
            float4 a1 = wqr[d+1], b1 = wkr[d+1];
            s0 += a0.x*b0.x + a0.y*b0.y + a0.z*b0.z + a0.w*b0.w;
            s1 += a1.x*b1.x + a1.y*b1.y + a1.z*b1.z + a1.w*b1.w;
        }
        Wcp[kc * 49152 + idx] = (s0 + s1) * SCALING_F;
    } else if (blk < 1280) {
        // --- Wvo partials, split-K x8 ---
        int bb = blk - 512;
        int kc = bb / 96;
        int ob = bb - kc * 96;
        int idx = ob * 256 + tid;    // 0..24575
        int g = idx / 768;
        int e = idx - g * 768;
        const float* wvr = Wkv + (size_t)g * 1536 + 768;
        int c0 = kc * 96;
        float s0 = 0.f, s1 = 0.f;
#pragma unroll 4
        for (int c = c0; c < c0 + 96; c += 2) {
            s0 += wvr[c]   * ln[c]   * Wout[(size_t)c * 768 + e];
            s1 += wvr[c+1] * ln[c+1] * Wout[(size_t)(c+1) * 768 + e];
        }
        Wvp[kc * 24576 + idx] = s0 + s1;
    } else {
        float s1 = 0.f, s2 = 0.f;
        for (int d = tid; d < 384; d += 256) {
            s1 += lq1[d] * lk1[d];
            s2 += lq2[d] * lk2[d];
        }
        s1 = waveSum(s1);
        s2 = waveSum(s2);
        __shared__ float r1[4], r2[4];
        int wid = tid >> 6, lane = tid & 63;
        if (lane == 0) { r1[wid] = s1; r2[wid] = s2; }
        __syncthreads();
        if (tid == 0) {
            float a  = r1[0] + r1[1] + r1[2] + r1[3];
            float b2 = r2[0] + r2[1] + r2[2] + r2[3];
            lam[0] = expf(a) - expf(b2) + LAM_INIT;
        }
    }
}

// ---------------------------------------------------------------------------
// K2 v3: tiled GEMM Qt = query @ Wcomb with split-K x4 -> Qtp partials.
// Blocks [0,512): kc = blk>>7, mt = blk&127 (32 m-rows). BK=64 chunks (3).
// As stored k-major [64][33] (padded), Bs[64][64] = Wcp0+Wcp1 summed on stage.
// Thread: tm=tid>>5 (4 m-rows), tn=tid&31 (2 n-cols) -> acc[4][2].
// Blocks [512,608): Wvo = sum of 8 Wvp partials.
// ---------------------------------------------------------------------------
__global__ __launch_bounds__(256) void k2_qt(
    const float* __restrict__ query, const float* __restrict__ Wcp,
    const float* __restrict__ Wvp, float* __restrict__ Wvo,
    float* __restrict__ Qtp)
{
    int blk = blockIdx.x;
    int tid = threadIdx.x;
    if (blk >= 512) {
        int idx = (blk - 512) * 256 + tid;   // 0..24575
        float s = 0.f;
#pragma unroll
        for (int kc = 0; kc < 8; ++kc) s += Wvp[kc * 24576 + idx];
        Wvo[idx] = s;
        return;
    }
    int kc = blk >> 7;          // 0..3
    int mt = blk & 127;
    int m0 = mt * 32;
    __shared__ __align__(16) float As[64 * 33];
    __shared__ __align__(16) float Bs[64 * 64];

    int tm = tid >> 5;          // 0..7 -> rows tm*4..+3
    int tn = tid & 31;          // cols tn*2, tn*2+1
    float acc[4][2];
#pragma unroll
    for (int r = 0; r < 4; ++r) { acc[r][0] = 0.f; acc[r][1] = 0.f; }

    for (int ch = 0; ch < 3; ++ch) {
        int k0 = kc * 192 + ch * 64;
        __syncthreads();
        // stage As (k-major, padded 33)
#pragma unroll
        for (int q = 0; q < 2; ++q) {
            int f = tid + q * 256;          // 0..511 float4s
            int m = f >> 4, kq = f & 15;
            float4 v = *(const float4*)&query[(size_t)(m0 + m) * 768 + k0 + kq * 4];
            As[(kq * 4 + 0) * 33 + m] = v.x;
            As[(kq * 4 + 1) * 33 + m] = v.y;
            As[(kq * 4 + 2) * 33 + m] = v.z;
            As[(kq * 4 + 3) * 33 + m] = v.w;
        }
        // stage Bs = Wcp0 + Wcp1
#pragma unroll
        for (int q = 0; q < 4; ++q) {
            int f = tid + q * 256;          // 0..1023 float4s
            int kk = f >> 4, n4 = f & 15;
            float4 a = *(const float4*)&Wcp[(size_t)(k0 + kk) * 64 + n4 * 4];
            float4 b = *(const float4*)&Wcp[49152 + (size_t)(k0 + kk) * 64 + n4 * 4];
            float4 s; s.x = a.x + b.x; s.y = a.y + b.y; s.z = a.z + b.z; s.w = a.w + b.w;
            *(float4*)&Bs[kk * 64 + n4 * 4] = s;
        }
        __syncthreads();
#pragma unroll 8
        for (int kk = 0; kk < 64; ++kk) {
            float4 a = *(const float4*)&As[kk * 33 + tm * 4];
            float2 b = *(const float2*)&Bs[kk * 64 + tn * 2];
            acc[0][0] += a.x * b.x; acc[0][1] += a.x * b.y;
            acc[1][0] += a.y * b.x; acc[1][1] += a.y * b.y;
            acc[2][0] += a.z * b.x; acc[2][1] += a.z * b.y;
            acc[3][0] += a.w * b.x; acc[3][1] += a.w * b.y;
        }
    }
#pragma unroll
    for (int r = 0; r < 4; ++r) {
        float2 o; o.x = acc[r][0]; o.y = acc[r][1];
        *(float2*)&Qtp[(size_t)kc * 262144 + (size_t)(m0 + tm * 4 + r) * 64 + tn * 2] = o;
    }
}

// ---------------------------------------------------------------------------
// K3 v5: fp16-dot2 scores -> masked softmax -> diff -> min-sub -> write.
// 1024 blocks x 512 threads; thread owns 8 l's; p[2][4][8] fp32 in regs.
// Qt summed from 4 partials, packed half2 in LDS [gp][ts*2+h].
// keyTh: packed half2 [b][gp][l] -> uint4 loads (4 l per load).
// ---------------------------------------------------------------------------
__global__ __launch_bounds__(512, 4) void k3_attn(
    const float* __restrict__ Qtp, const unsigned* __restrict__ keyThU,
    const int* __restrict__ qmask, const int* __restrict__ kmask,
    const float* __restrict__ lamp, float* __restrict__ diffO)
{
    int blk = blockIdx.x;
    int b  = blk >> 7;
    int s0 = (blk & 127) * 4;
    int tid = threadIdx.x;
    int lane = tid & 63, wid = tid >> 6;   // 8 waves

    __shared__ __align__(16) unsigned qt_th[128];  // [gp*8 + ts*2 + h]
    __shared__ float red[64];

    if (tid < 128) {
        int ts = tid >> 5;
        int h  = (tid >> 4) & 1;
        int gp = tid & 15;
        size_t row = (size_t)(b * 512 + s0 + ts) * 64;
        int col = h * 32 + 2 * gp;
        float v0 = 0.f, v1 = 0.f;
#pragma unroll
        for (int kc = 0; kc < 4; ++kc) {
            v0 += Qtp[(size_t)kc * 262144 + row + col];
            v1 += Qtp[(size_t)kc * 262144 + row + col + 1];
        }
        h2 hv; hv.x = (_Float16)v0; hv.y = (_Float16)v1;
        qt_th[gp * 8 + ts * 2 + h] = __builtin_bit_cast(unsigned, hv);
    }
    int qm[4];
#pragma unroll
    for (int ts = 0; ts < 4; ++ts) qm[ts] = qmask[b * 512 + s0 + ts];
    float lam = lamp[0];

    unsigned kmb = 0;
#pragma unroll
    for (int c = 0; c < 2; ++c) {
        int4 km = *(const int4*)(kmask + b * 4096 + c * 2048 + tid * 4);
        if (km.x) kmb |= 1u << (c * 4 + 0);
        if (km.y) kmb |= 1u << (c * 4 + 1);
        if (km.z) kmb |= 1u << (c * 4 + 2);
        if (km.w) kmb |= 1u << (c * 4 + 3);
    }
    __syncthreads();

    float p[2][4][8];
#pragma unroll
    for (int h = 0; h < 2; ++h)
#pragma unroll
        for (int ts = 0; ts < 4; ++ts)
#pragma unroll
            for (int i = 0; i < 8; ++i) p[h][ts][i] = 0.f;

    const unsigned* kt = keyThU + (size_t)b * 16 * 4096 + tid * 4;
    for (int gp = 0; gp < 16; ++gp) {
        uint4 q0 = *(const uint4*)&qt_th[gp * 8];
        uint4 q1 = *(const uint4*)&qt_th[gp * 8 + 4];
        h2 qv[8];
        qv[0] = __builtin_bit_cast(h2, q0.x); qv[1] = __builtin_bit_cast(h2, q0.y);
        qv[2] = __builtin_bit_cast(h2, q0.z); qv[3] = __builtin_bit_cast(h2, q0.w);
        qv[4] = __builtin_bit_cast(h2, q1.x); qv[5] = __builtin_bit_cast(h2, q1.y);
        qv[6] = __builtin_bit_cast(h2, q1.z); qv[7] = __builtin_bit_cast(h2, q1.w);
        const unsigned* kg = kt + (size_t)gp * 4096;
#pragma unroll
        for (int c = 0; c < 2; ++c) {
            uint4 kv = *(const uint4*)(kg + c * 2048);
            h2 k0 = __builtin_bit_cast(h2, kv.x);
            h2 k1 = __builtin_bit_cast(h2, kv.y);
            h2 k2 = __builtin_bit_cast(h2, kv.z);
            h2 k3 = __builtin_bit_cast(h2, kv.w);
#pragma unroll
            for (int ts = 0; ts < 4; ++ts)
#pragma unroll
                for (int h = 0; h < 2; ++h) {
                    h2 q = qv[ts * 2 + h];
                    p[h][ts][c*4+0] = FDOT2(k0, q, p[h][ts][c*4+0]);
                    p[h][ts][c*4+1] = FDOT2(k1, q, p[h][ts][c*4+1]);
                    p[h][ts][c*4+2] = FDOT2(k2, q, p[h][ts][c*4+2]);
                    p[h][ts][c*4+3] = FDOT2(k3, q, p[h][ts][c*4+3]);
                }
        }
    }

#pragma unroll
    for (int h = 0; h < 2; ++h)
#pragma unroll
        for (int ts = 0; ts < 4; ++ts)
#pragma unroll
            for (int i = 0; i < 8; ++i) {
                bool ok = qm[ts] && ((kmb >> i) & 1u);
                p[h][ts][i] = ok ? p[h][ts][i] : -1e20f;
            }

    float mrow[2][4];
#pragma unroll
    for (int h = 0; h < 2; ++h)
#pragma unroll
        for (int ts = 0; ts < 4; ++ts) {
            float v = -3.4e38f;
#pragma unroll
            for (int i = 0; i < 8; ++i) v = fmaxf(v, p[h][ts][i]);
            v = waveMax(v);
            if (lane == 0) red[(h * 4 + ts) * 8 + wid] = v;
        }
    __syncthreads();
#pragma unroll
    for (int h = 0; h < 2; ++h)
#pragma unroll
        for (int ts = 0; ts < 4; ++ts) {
            int r = (h * 4 + ts) * 8;
            float v = red[r];
#pragma unroll
            for (int w = 1; w < 8; ++w) v = fmaxf(v, red[r + w]);
            mrow[h][ts] = v;
        }
    __syncthreads();

    float inv[2][4];
#pragma unroll
    for (int h = 0; h < 2; ++h)
#pragma unroll
        for (int ts = 0; ts < 4; ++ts) {
            float s = 0.f;
#pragma unroll
            for (int i = 0; i < 8; ++i) {
                float e2 = __expf(p[h][ts][i] - mrow[h][ts]);
                p[h][ts][i] = e2;
                s += e2;
            }
            s = waveSum(s);
            if (lane == 0) red[(h * 4 + ts) * 8 + wid] = s;
        }
    __syncthreads();
#pragma unroll
    for (int h = 0; h < 2; ++h)
#pragma unroll
        for (int ts = 0; ts < 4; ++ts) {
            int r = (h * 4 + ts) * 8;
            float s = red[r];
#pragma unroll
            for (int w = 1; w < 8; ++w) s += red[r + w];
            inv[h][ts] = 1.0f / (s + 1e-8f);
        }
    __syncthreads();

    float mn[4];
#pragma unroll
    for (int ts = 0; ts < 4; ++ts) {
        float v = 3.4e38f;
#pragma unroll
        for (int i = 0; i < 8; ++i) {
            float d = p[0][ts][i] * inv[0][ts] - lam * (p[1][ts][i] * inv[1][ts]);
            p[0][ts][i] = d;
            v = fminf(v, d);
        }
        v = waveMin(v);
        if (lane == 0) red[ts * 8 + wid] = v;
    }
    __syncthreads();
#pragma unroll
    for (int ts = 0; ts < 4; ++ts) {
        int r = ts * 8;
        float v = red[r];
#pragma unroll
        for (int w = 1; w < 8; ++w) v = fminf(v, red[r + w]);
        mn[ts] = v;
    }

#pragma unroll
    for (int ts = 0; ts < 4; ++ts) {
        size_t base = (size_t)(b * 512 + s0 + ts) * 4096 + tid * 4;
#pragma unroll
        for (int c = 0; c < 2; ++c) {
            float4 o;
            float v0 = p[0][ts][c*4+0] - mn[ts] + 1e-20f;
            float v1 = p[0][ts][c*4+1] - mn[ts] + 1e-20f;
            float v2 = p[0][ts][c*4+2] - mn[ts] + 1e-20f;
            float v3 = p[0][ts][c*4+3] - mn[ts] + 1e-20f;
            o.x = (qm[ts] && ((kmb >> (c*4+0)) & 1u)) ? v0 : 0.f;
            o.y = (qm[ts] && ((kmb >> (c*4+1)) & 1u)) ? v1 : 0.f;
            o.z = (qm[ts] && ((kmb >> (c*4+2)) & 1u)) ? v2 : 0.f;
            o.w = (qm[ts] && ((kmb >> (c*4+3)) & 1u)) ? v3 : 0.f;
            *(float4*)(diffO + base + c * 2048) = o;
        }
    }
}

// ---------------------------------------------------------------------------
// K4 v3: T partials. 512 blocks = 64 row-tiles(64) x 8 k-chunks(512 l).
// Thread (tx=g-quad, ty -> 2 rows). Two 256-l LDS phases. Direct stores to P.
// ---------------------------------------------------------------------------
__global__ __launch_bounds__(256) void k4_T(
    const float* __restrict__ diff, const float* __restrict__ key,
    float* __restrict__ P)
{
    int blk = blockIdx.x;
    int rt = blk & 63, kc = blk >> 6;   // rt<64, kc<8
    int row0 = rt << 6;     // *64
    int b = row0 >> 9;
    int l0 = kc << 9;       // *512
    int tid = threadIdx.x;
    int tx = tid & 7;       // g0 = tx*4
    int ty = tid >> 3;      // rows row0 + ty*2 + r
    int g0 = tx * 4;

    __shared__ __align__(16) float Ks[256][32];

    float acc[2][4];
#pragma unroll
    for (int r = 0; r < 2; ++r)
#pragma unroll
        for (int c2 = 0; c2 < 4; ++c2) acc[r][c2] = 0.f;

    for (int ph = 0; ph < 2; ++ph) {
        int lp = l0 + ph * 256;
        __syncthreads();
#pragma unroll
        for (int q = 0; q < 32; ++q) {
            int idx = tid + (q << 8);
            int r = idx >> 5, g = idx & 31;
            Ks[r][g] = key[((size_t)(b * 4096 + lp + r)) * 32 + g];
        }
        __syncthreads();

        for (int j4 = 0; j4 < 64; ++j4) {
            int l = lp + j4 * 4;
            float4 dv[2];
#pragma unroll
            for (int r = 0; r < 2; ++r)
                dv[r] = *(const float4*)(diff + (size_t)(row0 + ty * 2 + r) * 4096 + l);
#pragma unroll
            for (int jj = 0; jj < 4; ++jj) {
                float4 kq = *(const float4*)&Ks[j4 * 4 + jj][g0];
#pragma unroll
                for (int r = 0; r < 2; ++r) {
                    float d = (jj == 0) ? dv[r].x : (jj == 1) ? dv[r].y : (jj == 2) ? dv[r].z : dv[r].w;
                    acc[r][0] += d * kq.x;
                    acc[r][1] += d * kq.y;
                    acc[r][2] += d * kq.z;
                    acc[r][3] += d * kq.w;
                }
            }
        }
    }
#pragma unroll
    for (int r = 0; r < 2; ++r) {
        float4 o; o.x = acc[r][0]; o.y = acc[r][1]; o.z = acc[r][2]; o.w = acc[r][3];
        *(float4*)&P[(size_t)kc * 131072 + (size_t)(row0 + ty * 2 + r) * 32 + g0] = o;
    }
}

// ---------------------------------------------------------------------------
// K5: reduce T = sum_kc P[kc], RMS statistic from a = T@Wv, out = 0.8*rs*(T@Wvo)
// 512 blocks x 8 rows.
// ---------------------------------------------------------------------------
__global__ __launch_bounds__(256) void k5_out(
    const float* __restrict__ P, const float* __restrict__ Wkv,
    const float* __restrict__ Wvo, float* __restrict__ out)
{
    int row0 = blockIdx.x * 8;
    int tid = threadIdx.x;
    int wid = tid >> 6, lane = tid & 63;
    __shared__ __align__(16) float Ts[8][32];
    __shared__ float red[8][4];
    __shared__ float rs_s[8];

    {
        int r = tid >> 5, g = tid & 31;
        float s = 0.f;
#pragma unroll
        for (int kc = 0; kc < 8; ++kc)
            s += P[(size_t)kc * 131072 + (size_t)(row0 + r) * 32 + g];
        Ts[r][g] = s;
    }
    __syncthreads();

    float ssq[8];
#pragma unroll
    for (int r = 0; r < 8; ++r) ssq[r] = 0.f;

#pragma unroll
    for (int ec = 0; ec < 3; ++ec) {
        int e = tid + ec * 256;
        float wv[32];
#pragma unroll
        for (int g = 0; g < 32; ++g) wv[g] = Wkv[(size_t)g * 1536 + 768 + e];
#pragma unroll
        for (int r = 0; r < 8; ++r) {
            float a = 0.f;
#pragma unroll
            for (int g = 0; g < 32; ++g) a += Ts[r][g] * wv[g];
            ssq[r] += a * a;
        }
    }
#pragma unroll
    for (int r = 0; r < 8; ++r) {
        float v = waveSum(ssq[r]);
        if (lane == 0) red[r][wid] = v;
    }
    __syncthreads();
    if (tid < 8) {
        float s = red[tid][0] + red[tid][1] + red[tid][2] + red[tid][3];
        float ms = s * (1.0f / 768.0f);
        rs_s[tid] = rsqrtf(ms + 1e-5f) * ONE_MINUS_LAM;
    }
    __syncthreads();

#pragma unroll
    for (int ec = 0; ec < 3; ++ec) {
        int e = tid + ec * 256;
        float wo[32];
#pragma unroll
        for (int g = 0; g < 32; ++g) wo[g] = Wvo[(size_t)g * 768 + e];
#pragma unroll
        for (int r = 0; r < 8; ++r) {
            float o = 0.f;
#pragma unroll
            for (int g = 0; g < 32; ++g) o += Ts[r][g] * wo[g];
            out[(size_t)(row0 + r) * 768 + e] = o * rs_s[r];
        }
    }
}

// ---------------------------------------------------------------------------
extern "C" void kernel_launch(void* const* d_in, const int* in_sizes, int n_in,
                              void* d_out, int out_size, void* d_ws, size_t ws_size,
                              hipStream_t stream) {
    (void)in_sizes; (void)n_in; (void)out_size; (void)ws_size;
    const float* query = (const float*)d_in[0];
    const float* key   = (const float*)d_in[1];
    const int*   qmask = (const int*)d_in[2];
    const int*   kmask = (const int*)d_in[3];
    const float* Wq    = (const float*)d_in[4];
    const float* Wkv   = (const float*)d_in[5];
    const float* Wout  = (const float*)d_in[6];
    const float* lq1   = (const float*)d_in[7];
    const float* lk1   = (const float*)d_in[8];
    const float* lq2   = (const float*)d_in[9];
    const float* lk2   = (const float*)d_in[10];
    const float* ln    = (const float*)d_in[11];

    float* out  = (float*)d_out;          // (B,S,E) = 3,145,728 floats
    float* diff = out + 3145728;          // (B,S,L) = 16,777,216 floats

    float* ws      = (float*)d_ws;
    float* Wcp     = ws;                    // 98304  (2 Wcomb partials)
    float* Wvo     = ws + 98304;            // 24576
    float* Wvp     = ws + 122880;           // 196608 (8 Wvo partials)
    float* lam     = ws + 319488;           // 64
    unsigned* keyThU = (unsigned*)(ws + 319552); // 524288 u32 (half2-packed keyT)
    float* Qtp     = ws + 843840;           // 1048576 (4 Qt partials)
    float* P       = Qtp;                   // alias: Qtp dead after k3; P written by k4
                                            // total ~7.6 MB

    k01_prep<<<1281, 256, 0, stream>>>(key, Wq, Wkv, Wout, lq1, lk1, lq2, lk2, ln,
                                       keyThU, Wcp, Wvp, lam);
    k2_qt<<<608, 256, 0, stream>>>(query, Wcp, Wvp, Wvo, Qtp);
    k3_attn<<<1024, 512, 0, stream>>>(Qtp, keyThU, qmask, kmask, lam, diff);
    k4_T<<<512, 256, 0, stream>>>(diff, key, P);
    k5_out<<<512, 256, 0, stream>>>(P, Wkv, Wvo, out);
}